// Round 12
// baseline (432.084 us; speedup 1.0000x reference)
//
#include <hip/hip_runtime.h>
#include <math.h>

typedef __attribute__((ext_vector_type(8))) short bf16x8;
typedef __attribute__((ext_vector_type(4))) float f32x4;
typedef unsigned short ushort_t;
typedef unsigned int uint_t;

__device__ __forceinline__ float lrelu_f(float x) { return x >= 0.f ? x : 0.01f * x; }

__device__ __forceinline__ ushort_t f2bf(float f) {
    uint_t x = __float_as_uint(f);
    uint_t r = (x + 0x7fffu + ((x >> 16) & 1u)) >> 16;
    return (ushort_t)r;
}

__device__ __forceinline__ uint_t pack_bf16(float lo, float hi) {
    uint_t out;
    asm("v_cvt_pk_bf16_f32 %0, %1, %2" : "=v"(out) : "v"(lo), "v"(hi));
    return out;
}

__device__ __forceinline__ float fexp2(float x) {
    float r;
    asm("v_exp_f32 %0, %1" : "=v"(r) : "v"(x));
    return r;
}

// ===========================================================================
// Weight prep: w2[co64][K'] bf16, channel-block-major K ordering.
// ===========================================================================
__global__ __launch_bounds__(256) void castw2_kernel(const float* __restrict__ w,
    ushort_t* __restrict__ w2, int Cout, int Cin, int K, int deconv)
{
    int idx = blockIdx.x * 256 + threadIdx.x;
    if (idx >= 64 * K) return;
    int co = idx / K, kp = idx % K;
    int cb = kp / 288;
    int r  = kp % 288;
    int tap = r >> 5, cl = r & 31;
    int ci = cb * 32 + cl;
    float val = 0.f;
    if (co < Cout)
        val = deconv ? w[(size_t)(ci * Cout + co) * 9 + (8 - tap)]
                     : w[(size_t)(co * Cin + ci) * 9 + tap];
    w2[idx] = f2bf(val);
}

// ===========================================================================
// bf16 MFMA implicit-GEMM 3x3 conv over 4-batch, double-buffered staging:
// prefetch chunk k+1 (global loads + LDS write to other buffer) before the
// MFMAs on chunk k; one barrier per chunk.
// ===========================================================================
template<int STRIDE, int MODE>
__global__ __launch_bounds__(256) void conv3x3_mfma(
    const float* __restrict__ inA, const float* __restrict__ inB, int CinA,
    size_t sStrideA, int Hin, int Win, int Cin,
    const ushort_t* __restrict__ w2, int K,
    int Wout, int Npx, int tilesPerMap, int ksplit, int chunksPerKs,
    float* __restrict__ part,
    const float* __restrict__ bias, int act, int CoutStore, float* __restrict__ outDirect)
{
    __shared__ ushort_t sB[2][64 * 40];
    int tile = blockIdx.x % tilesPerMap;
    int ks   = (blockIdx.x / tilesPerMap) % ksplit;
    int b4   = blockIdx.x / (tilesPerMap * ksplit);
    int s_idx = b4 >> 1, bb = b4 & 1;
    int tid  = threadIdx.x;
    int wave = tid >> 6, lane = tid & 63;
    int lrow = lane & 15, lkg = lane >> 4;
    int px  = tid & 63;
    int cio = wave * 8;
    int p   = tile * 64 + px;
    int oy  = p / Wout, ox = p - oy * Wout;
    int HWin = Hin * Win;
    int CinB = Cin - CinA;

    auto stage_pk = [&](int chunkIdx) -> uint4 {
        int cb  = chunkIdx / 9;
        int tap = chunkIdx - cb * 9;
        int cib = cb * 32;
        int ky = tap / 3, kx = tap - ky * 3;
        float msk;
        int offp;
        if (MODE == 0) {
            int iy = oy * STRIDE - 1 + ky;
            int ix = ox * STRIDE - 1 + kx;
            bool vld = (iy >= 0) && (iy < Hin) && (ix >= 0) && (ix < Win);
            msk = vld ? 1.f : 0.f;
            offp = min(max(iy, 0), Hin - 1) * Win + min(max(ix, 0), Win - 1);
        } else {
            int uy = oy + ky, ux = ox + kx;
            int r = (uy - 1) >> 1, q = (ux - 1) >> 1;
            bool vld = (uy & 1) && (ux & 1) && (r < Hin) && (q < Win);
            msk = vld ? 1.f : 0.f;
            offp = min(max(r, 0), Hin - 1) * Win + min(max(q, 0), Win - 1);
        }
        int c = cib + cio;
        const float* src = (c < CinA)
            ? inA + s_idx * sStrideA + (size_t)(bb * CinA + c) * HWin
            : inB + (size_t)(bb * CinB + (c - CinA)) * HWin;
        float v[8];
        #pragma unroll
        for (int j = 0; j < 8; ++j) v[j] = src[(size_t)j * HWin + offp] * msk;
        uint4 pk;
        pk.x = pack_bf16(v[0], v[1]);
        pk.y = pack_bf16(v[2], v[3]);
        pk.z = pack_bf16(v[4], v[5]);
        pk.w = pack_bf16(v[6], v[7]);
        return pk;
    };

    f32x4 acc[4];
    #pragma unroll
    for (int n2 = 0; n2 < 4; ++n2) acc[n2] = (f32x4){0.f, 0.f, 0.f, 0.f};

    int chunk0 = ks * chunksPerKs;
    {
        uint4 pk = stage_pk(chunk0);
        *(uint4*)&sB[0][px * 40 + cio] = pk;
    }
    __syncthreads();

    int cur = 0;
    for (int cch = 0; cch < chunksPerKs; ++cch) {
        if (cch + 1 < chunksPerKs) {
            uint4 pk = stage_pk(chunk0 + cch + 1);
            *(uint4*)&sB[cur ^ 1][px * 40 + cio] = pk;
        }
        const ushort_t* wr = w2 + (size_t)(wave * 16 + lrow) * K + (chunk0 + cch) * 32 + lkg * 8;
        bf16x8 afr = *(const bf16x8*)wr;
        #pragma unroll
        for (int n2 = 0; n2 < 4; ++n2) {
            bf16x8 bfr = *(const bf16x8*)&sB[cur][(n2 * 16 + lrow) * 40 + lkg * 8];
            acc[n2] = __builtin_amdgcn_mfma_f32_16x16x32_bf16(afr, bfr, acc[n2], 0, 0, 0);
        }
        __syncthreads();
        cur ^= 1;
    }

    if (bias) {
        #pragma unroll
        for (int n2 = 0; n2 < 4; ++n2) {
            #pragma unroll
            for (int j = 0; j < 4; ++j) {
                int co = wave * 16 + lkg * 4 + j;
                if (co < CoutStore) {
                    int pp = tile * 64 + n2 * 16 + lrow;
                    float r = acc[n2][j] + bias[co];
                    if (act) r = lrelu_f(r);
                    outDirect[((size_t)(b4 * CoutStore + co)) * (size_t)Npx + pp] = r;
                }
            }
        }
    } else {
        #pragma unroll
        for (int n2 = 0; n2 < 4; ++n2) {
            #pragma unroll
            for (int j = 0; j < 4; ++j) {
                int co = wave * 16 + lkg * 4 + j;
                int pp = tile * 64 + n2 * 16 + lrow;
                part[((size_t)(ks * 4 + b4) * 64 + co) * (size_t)Npx + pp] = acc[n2][j];
            }
        }
    }
}

__global__ __launch_bounds__(256) void reduce_bias_act(const float* __restrict__ part,
    const float* __restrict__ bias, float* __restrict__ out,
    int Cout, int Npx, int ksplit, int act)
{
    int idx = blockIdx.x * 256 + threadIdx.x;
    int total = 4 * Cout * Npx;
    if (idx >= total) return;
    int p  = idx % Npx;
    int co = (idx / Npx) % Cout;
    int b4 = idx / (Npx * Cout);
    float s = bias[co];
    for (int ks = 0; ks < ksplit; ++ks)
        s += part[(((size_t)ks * 4 + b4) * 64 + co) * (size_t)Npx + p];
    if (act) s = lrelu_f(s);
    out[((size_t)b4 * Cout + co) * (size_t)Npx + p] = s;
}

__global__ __launch_bounds__(256) void castw_perm_kernel(const float* __restrict__ w,
    ushort_t* __restrict__ wbf)
{
    int idx = blockIdx.x * 256 + threadIdx.x;
    if (idx >= 147456) return;
    int co = idx / 1152;
    int r  = idx % 1152;
    int chunk = r / 288;
    int r2 = r % 288;
    int tap = r2 >> 5;
    int cl  = r2 & 31;
    int ci = chunk * 32 + cl;
    wbf[idx] = f2bf(w[(size_t)co * 1152 + ci * 9 + tap]);
}

// Batched NCHW frames (s=1,2) -> NHWC bf16 [b4][16384][128]
__global__ __launch_bounds__(256) void transpose_nhwc_bf16(const float* __restrict__ x,
    ushort_t* __restrict__ xT)
{
    __shared__ float t[32][33];
    int cT = blockIdx.x & 3;
    int pT = (blockIdx.x >> 2) & 511;
    int b4 = blockIdx.x >> 11;
    int tx = threadIdx.x & 31, ty = threadIdx.x >> 5;
    const float* src = x + ((size_t)((b4 + 2) * 128) + cT * 32) * 16384 + (size_t)pT * 32;
    #pragma unroll
    for (int i = 0; i < 4; ++i)
        t[ty + 8 * i][tx] = src[(size_t)(ty + 8 * i) * 16384 + tx];
    __syncthreads();
    ushort_t* dst = xT + ((size_t)b4 * 16384 + (size_t)pT * 32) * 128 + cT * 32;
    #pragma unroll
    for (int i = 0; i < 4; ++i)
        dst[(size_t)(ty + 8 * i) * 128 + tx] = f2bf(t[tx][ty + 8 * i]);
}

// ---------------------------------------------------------------------------
// Fused 1x1 convs -> bf16 attention operands, 4-batch (thT pre-scaled log2e).
// ---------------------------------------------------------------------------
__global__ __launch_bounds__(256) void conv1x1x3_bf16(const float* __restrict__ e, int N,
    const float* __restrict__ tw, const float* __restrict__ tb,
    const float* __restrict__ pw, const float* __restrict__ pb,
    const float* __restrict__ gw, const float* __restrict__ gb,
    ushort_t* __restrict__ thT, ushort_t* __restrict__ phT, ushort_t* __restrict__ gT)
{
    __shared__ float sw[32 * 64];
    __shared__ float sb[32];
    int tid = threadIdx.x;
    int idx = blockIdx.x * 256 + tid;
    int j = idx / (4 * N);
    const float* wsel = (j == 0) ? tw : (j == 1) ? pw : gw;
    const float* bsel = (j == 0) ? tb : (j == 1) ? pb : gb;
    for (int i = tid; i < 2048; i += 256) sw[i] = wsel[i];
    if (tid < 32) sb[tid] = bsel[tid];
    __syncthreads();
    int rem = idx - j * 4 * N;
    int n = rem % N, b4 = rem / N;
    float ein[64];
    const float* ep = e + (size_t)b4 * 64 * N + n;
    #pragma unroll
    for (int ci = 0; ci < 64; ++ci) ein[ci] = ep[(size_t)ci * N];

    float val[32];
    #pragma unroll
    for (int cc = 0; cc < 32; ++cc) {
        float acc = sb[cc];
        const float* wr = &sw[cc * 64];
        #pragma unroll
        for (int ci = 0; ci < 64; ++ci) acc = fmaf(wr[ci], ein[ci], acc);
        val[cc] = acc;
    }
    if (j == 0) {
        #pragma unroll
        for (int cc = 0; cc < 32; ++cc) val[cc] *= 1.44269504f;
    }
    if (j < 2) {
        ushort_t* row = (j == 0 ? thT : phT) + ((size_t)b4 * N + n) * 32;
        #pragma unroll
        for (int w4 = 0; w4 < 4; ++w4) {
            uint4 pk;
            pk.x = pack_bf16(val[8 * w4 + 0], val[8 * w4 + 1]);
            pk.y = pack_bf16(val[8 * w4 + 2], val[8 * w4 + 3]);
            pk.z = pack_bf16(val[8 * w4 + 4], val[8 * w4 + 5]);
            pk.w = pack_bf16(val[8 * w4 + 6], val[8 * w4 + 7]);
            *(uint4*)(row + 8 * w4) = pk;
        }
    } else {
        #pragma unroll
        for (int cc = 0; cc < 32; ++cc)
            gT[((size_t)b4 * 32 + cc) * N + n] = f2bf(val[cc]);
    }
}

// ===========================================================================
// Flash split-K MFMA attention (exp2 domain, defer-max), 4-batch.
// ===========================================================================
__global__ __launch_bounds__(256) void attn_flash(const ushort_t* __restrict__ thT,
    const ushort_t* __restrict__ phT, const ushort_t* __restrict__ gT,
    float* __restrict__ partO, float* __restrict__ partML, int N, int KVS)
{
    __shared__ ushort_t sP[4][16 * 40];
    int tid  = threadIdx.x;
    int wave = tid >> 6, lane = tid & 63;
    int lq = lane & 15, lkg = lane >> 4;
    int nqb = N / 64;
    int ks = blockIdx.x % KVS;
    int qb = (blockIdx.x / KVS) % nqb;
    int b4 = blockIdx.x / (KVS * nqb);
    int q0w = qb * 64 + wave * 16;
    int chunk = N / KVS;
    int m_start = ks * chunk;

    bf16x8 qf = *(const bf16x8*)(thT + ((size_t)b4 * N + q0w + lq) * 32 + 8 * lkg);

    float m_run = -1e30f, l_run = 0.f;
    f32x4 acc[2];
    acc[0] = (f32x4){0.f, 0.f, 0.f, 0.f};
    acc[1] = (f32x4){0.f, 0.f, 0.f, 0.f};

    for (int m0 = m_start; m0 < m_start + chunk; m0 += 64) {
        f32x4 tf[4];
        #pragma unroll
        for (int f = 0; f < 4; ++f) {
            bf16x8 kf = *(const bf16x8*)(phT + ((size_t)b4 * N + m0 + f * 16 + lq) * 32 + 8 * lkg);
            tf[f] = __builtin_amdgcn_mfma_f32_16x16x32_bf16(kf, qf,
                        (f32x4){0.f, 0.f, 0.f, 0.f}, 0, 0, 0);
        }

        float mx = -1e30f;
        #pragma unroll
        for (int f = 0; f < 4; ++f)
            #pragma unroll
            for (int r = 0; r < 4; ++r) mx = fmaxf(mx, tf[f][r]);
        mx = fmaxf(mx, __shfl_xor(mx, 16));
        mx = fmaxf(mx, __shfl_xor(mx, 32));

        if (__any(mx > m_run)) {
            float m_new = fmaxf(m_run, mx);
            float scale = fexp2(m_run - m_new);
            l_run *= scale;
            m_run = m_new;
            float sc[4];
            #pragma unroll
            for (int r = 0; r < 4; ++r) sc[r] = __shfl(scale, 4 * lkg + r);
            #pragma unroll
            for (int h = 0; h < 2; ++h)
                #pragma unroll
                for (int r = 0; r < 4; ++r) acc[h][r] *= sc[r];
        }

        float rs = 0.f;
        #pragma unroll
        for (int f = 0; f < 4; ++f)
            #pragma unroll
            for (int r = 0; r < 4; ++r) {
                float pv = fexp2(tf[f][r] - m_run);
                tf[f][r] = pv;
                rs += pv;
            }
        rs += __shfl_xor(rs, 16);
        rs += __shfl_xor(rs, 32);
        l_run += rs;

        #pragma unroll
        for (int f = 0; f < 4; ++f) {
            *(uint_t*)&sP[wave][lq * 40 + f * 16 + 4 * lkg]     = pack_bf16(tf[f][0], tf[f][1]);
            *(uint_t*)&sP[wave][lq * 40 + f * 16 + 4 * lkg + 2] = pack_bf16(tf[f][2], tf[f][3]);
        }

        #pragma unroll
        for (int mc = 0; mc < 2; ++mc) {
            bf16x8 pf = *(const bf16x8*)&sP[wave][lq * 40 + mc * 32 + 8 * lkg];
            #pragma unroll
            for (int h = 0; h < 2; ++h) {
                bf16x8 vf = *(const bf16x8*)(gT + ((size_t)b4 * 32 + h * 16 + lq) * N
                                             + m0 + mc * 32 + 8 * lkg);
                acc[h] = __builtin_amdgcn_mfma_f32_16x16x32_bf16(pf, vf, acc[h], 0, 0, 0);
            }
        }
    }

    #pragma unroll
    for (int h = 0; h < 2; ++h) {
        #pragma unroll
        for (int r = 0; r < 4; ++r) {
            int q = q0w + 4 * lkg + r;
            partO[(((size_t)ks * 4 + b4) * N + q) * 32 + h * 16 + lq] = acc[h][r];
        }
    }
    if (lane < 16) {
        size_t mlo = (((size_t)ks * 4 + b4) * N + q0w + lq) * 2;
        partML[mlo]     = m_run;
        partML[mlo + 1] = l_run;
    }
}

// ===========================================================================
// Fused flash-combine (exp2 domain) + non-local merge (4-batch).
// ===========================================================================
__global__ __launch_bounds__(256) void nl_merge_fused(const float* __restrict__ e,
    const float* __restrict__ partO, const float* __restrict__ partML,
    const float* __restrict__ u,
    const float* __restrict__ ww, const float* __restrict__ wb,
    float* __restrict__ out, int N, int KVS)
{
    __shared__ float sw[64 * 32];
    __shared__ float sb[64];
    int tid = threadIdx.x;
    for (int i = tid; i < 2048; i += 256) sw[i] = ww[i];
    if (tid < 64) sb[tid] = wb[tid];
    __syncthreads();
    int idx = blockIdx.x * 256 + tid;
    int n = idx % N;
    int cog = (idx / N) & 3;
    int b4 = idx / (4 * N);

    float mstar = -1e30f;
    for (int ks = 0; ks < KVS; ++ks)
        mstar = fmaxf(mstar, partML[(((size_t)ks * 4 + b4) * N + n) * 2]);
    float denom = 0.f;
    float yv[32];
    #pragma unroll
    for (int c = 0; c < 32; ++c) yv[c] = 0.f;
    for (int ks = 0; ks < KVS; ++ks) {
        size_t mlo = (((size_t)ks * 4 + b4) * N + n) * 2;
        float w = fexp2(partML[mlo] - mstar);
        denom += w * partML[mlo + 1];
        const f32x4* op = (const f32x4*)(partO + (((size_t)ks * 4 + b4) * N + n) * 32);
        #pragma unroll
        for (int jj = 0; jj < 8; ++jj) {
            f32x4 v = op[jj];
            #pragma unroll
            for (int t = 0; t < 4; ++t) yv[4 * jj + t] = fmaf(w, v[t], yv[4 * jj + t]);
        }
    }
    float inv = 1.f / denom;
    #pragma unroll
    for (int i = 0; i < 16; ++i) {
        int co = cog * 16 + i;
        float dot = 0.f;
        const float* wr = &sw[co * 32];
        #pragma unroll
        for (int c = 0; c < 32; ++c) dot = fmaf(wr[c], yv[c], dot);
        size_t o = (size_t)b4 * 64 * N + (size_t)co * N + n;
        float r = sb[co] + inv * dot + 2.f * e[o];
        if (u) r += u[o];
        out[o] = r;
    }
}

// ===========================================================================
// Deformable conv v5: sampling params in per-thread REGISTERS (9 entries,
// fully unrolled static indexing), LDS = sB only (37.9KB) -> 4 blocks/CU.
// bf16 NHWC input, 8-ch 16B gathers, batched 4 images, XCD-swizzled.
// ===========================================================================
__global__ __launch_bounds__(256, 4) void deform_mfma5(const ushort_t* __restrict__ xT,
    const float* __restrict__ est, const ushort_t* __restrict__ wbf,
    const float* __restrict__ bias, float* __restrict__ out)
{
    const int H = 128, W = 128, HW = 16384;
    const int BS = 296;
    __shared__ ushort_t sB[64 * BS];
    int id  = blockIdx.x;                       // 1024 blocks, %8==0
    int lin = (id & 7) * 128 + (id >> 3);       // XCD-chunked bijective remap
    int tile = lin & 255;
    int b4   = lin >> 8;                        // 0..3, image = b4+2
    int p0   = tile * 64;
    int tid  = threadIdx.x;

    // ---- per-thread sampling params (si = (it*256+tid)>>2, static index)
    float4 rW[9];
    uint2  rO[9];
    const float* eb = est + (size_t)b4 * 27 * HW;
    #pragma unroll
    for (int it = 0; it < 9; ++it) {
        int si = (it * 256 + tid) >> 2;
        int k = si >> 6, j = si & 63;
        int p = p0 + j;
        int yy = p >> 7, xx = p & 127;
        float oy = eb[(size_t)(9 + 2 * k) * HW + p];
        float ox = eb[(size_t)(10 + 2 * k) * HW + p];
        float mv = eb[(size_t)k * HW + p];
        float mk = 1.f / (1.f + __expf(-mv));
        float py = (float)(yy + (k / 3) - 1) + oy;
        float qx = (float)(xx + (k % 3) - 1) + ox;
        float fy0 = floorf(py), fx0 = floorf(qx);
        float wy = py - fy0, wx = qx - fx0;
        int y0 = (int)fy0, x0 = (int)fx0;
        int y1 = y0 + 1, x1 = x0 + 1;
        bool yv0 = (y0 >= 0) && (y0 < H), yv1 = (y1 >= 0) && (y1 < H);
        bool xv0 = (x0 >= 0) && (x0 < W), xv1 = (x1 >= 0) && (x1 < W);
        int y0c = min(max(y0, 0), H - 1), y1c = min(max(y1, 0), H - 1);
        int x0c = min(max(x0, 0), W - 1), x1c = min(max(x1, 0), W - 1);
        float4 w4;
        w4.x = (yv0 && xv0) ? (1.f - wy) * (1.f - wx) * mk : 0.f;
        w4.y = (yv0 && xv1) ? (1.f - wy) * wx * mk : 0.f;
        w4.z = (yv1 && xv0) ? wy * (1.f - wx) * mk : 0.f;
        w4.w = (yv1 && xv1) ? wy * wx * mk : 0.f;
        rW[it] = w4;
        uint_t o00 = (uint_t)(y0c * W + x0c), o01 = (uint_t)(y0c * W + x1c);
        uint_t o10 = (uint_t)(y1c * W + x0c), o11 = (uint_t)(y1c * W + x1c);
        rO[it] = (uint2){ o00 | (o01 << 16), o10 | (o11 << 16) };
    }

    int wave = tid >> 6, lane = tid & 63;
    int co_base = wave * 32;
    int lrow = lane & 15, lkg = lane >> 4;
    int cg  = tid & 3;                  // channel group (8 ch)
    int pxl_base = (tid >> 2);          // si = it*64 + pxl_base? no: si=(it*256+tid)>>2

    f32x4 acc[2][4];
    #pragma unroll
    for (int m2 = 0; m2 < 2; ++m2)
        #pragma unroll
        for (int n2 = 0; n2 < 4; ++n2) acc[m2][n2] = (f32x4){0.f, 0.f, 0.f, 0.f};

    const ushort_t* xb = xT + (size_t)b4 * HW * 128;

    for (int cc = 0; cc < 128; cc += 32) {
        __syncthreads();
        #pragma unroll
        for (int it = 0; it < 9; ++it) {
            int si = (it * 256 + tid) >> 2;
            float4 w4 = rW[it];
            uint2 o4 = rO[it];
            int chb = cc + cg * 8;
            uint4 u00 = *(const uint4*)(xb + (size_t)(o4.x & 0xFFFFu) * 128 + chb);
            uint4 u01 = *(const uint4*)(xb + (size_t)(o4.x >> 16) * 128 + chb);
            uint4 u10 = *(const uint4*)(xb + (size_t)(o4.y & 0xFFFFu) * 128 + chb);
            uint4 u11 = *(const uint4*)(xb + (size_t)(o4.y >> 16) * 128 + chb);
            float v[8];
            const uint_t* a0 = (const uint_t*)&u00;
            const uint_t* a1 = (const uint_t*)&u01;
            const uint_t* a2 = (const uint_t*)&u10;
            const uint_t* a3 = (const uint_t*)&u11;
            #pragma unroll
            for (int q = 0; q < 4; ++q) {
                float c00l = __uint_as_float(a0[q] << 16), c00h = __uint_as_float(a0[q] & 0xffff0000u);
                float c01l = __uint_as_float(a1[q] << 16), c01h = __uint_as_float(a1[q] & 0xffff0000u);
                float c10l = __uint_as_float(a2[q] << 16), c10h = __uint_as_float(a2[q] & 0xffff0000u);
                float c11l = __uint_as_float(a3[q] << 16), c11h = __uint_as_float(a3[q] & 0xffff0000u);
                v[2 * q]     = w4.x * c00l + w4.y * c01l + w4.z * c10l + w4.w * c11l;
                v[2 * q + 1] = w4.x * c00h + w4.y * c01h + w4.z * c10h + w4.w * c11h;
            }
            int pxl = si & 63, tap = si >> 6;
            uint4 pk;
            pk.x = pack_bf16(v[0], v[1]);
            pk.y = pack_bf16(v[2], v[3]);
            pk.z = pack_bf16(v[4], v[5]);
            pk.w = pack_bf16(v[6], v[7]);
            *(uint4*)&sB[pxl * BS + tap * 32 + cg * 8] = pk;
        }
        __syncthreads();
        int kbase = cc * 9;
        #pragma unroll
        for (int ks = 0; ks < 9; ++ks) {
            bf16x8 afr[2], bfr[4];
            #pragma unroll
            for (int m2 = 0; m2 < 2; ++m2)
                afr[m2] = *reinterpret_cast<const bf16x8*>(
                    wbf + (size_t)(co_base + m2 * 16 + lrow) * 1152 + kbase + ks * 32 + lkg * 8);
            #pragma unroll
            for (int n2 = 0; n2 < 4; ++n2)
                bfr[n2] = *reinterpret_cast<const bf16x8*>(
                    &sB[(n2 * 16 + lrow) * BS + ks * 32 + lkg * 8]);
            #pragma unroll
            for (int m2 = 0; m2 < 2; ++m2)
                #pragma unroll
                for (int n2 = 0; n2 < 4; ++n2)
                    acc[m2][n2] = __builtin_amdgcn_mfma_f32_16x16x32_bf16(
                        afr[m2], bfr[n2], acc[m2][n2], 0, 0, 0);
        }
    }

    #pragma unroll
    for (int m2 = 0; m2 < 2; ++m2) {
        #pragma unroll
        for (int j = 0; j < 4; ++j) {
            int co = co_base + m2 * 16 + lkg * 4 + j;
            float bb = bias[co];
            #pragma unroll
            for (int n2 = 0; n2 < 4; ++n2) {
                int px = p0 + n2 * 16 + lrow;
                out[((size_t)((b4 + 2) * 128 + co)) * HW + px] = acc[m2][n2][j] + bb;
            }
        }
    }
}

extern "C" void kernel_launch(void* const* d_in, const int* in_sizes, int n_in,
                              void* d_out, int out_size, void* d_ws, size_t ws_size,
                              hipStream_t stream)
{
    const float* x_all     = (const float*)d_in[0];
    const float* ms_fine   = (const float*)d_in[1];
    const float* ms_coarse = (const float*)d_in[2];
    const float* enc_w0 = (const float*)d_in[3];
    const float* enc_b0 = (const float*)d_in[4];
    const float* enc_w1 = (const float*)d_in[5];
    const float* enc_b1 = (const float*)d_in[6];
    const float* nl_tw[2] = { (const float*)d_in[7],  (const float*)d_in[15] };
    const float* nl_tb[2] = { (const float*)d_in[8],  (const float*)d_in[16] };
    const float* nl_pw[2] = { (const float*)d_in[9],  (const float*)d_in[17] };
    const float* nl_pb[2] = { (const float*)d_in[10], (const float*)d_in[18] };
    const float* nl_gw[2] = { (const float*)d_in[11], (const float*)d_in[19] };
    const float* nl_gb[2] = { (const float*)d_in[12], (const float*)d_in[20] };
    const float* nl_ww[2] = { (const float*)d_in[13], (const float*)d_in[21] };
    const float* nl_wb[2] = { (const float*)d_in[14], (const float*)d_in[22] };
    const float* dec_w0 = (const float*)d_in[23];
    const float* dec_b0 = (const float*)d_in[24];
    const float* dec_w1 = (const float*)d_in[25];
    const float* dec_b1 = (const float*)d_in[26];
    const float* off_w  = (const float*)d_in[27];
    const float* off_b  = (const float*)d_in[28];
    const float* dcn_w  = (const float*)d_in[29];
    const float* dcn_b  = (const float*)d_in[30];

    // ---- workspace layout (floats), lifetime-overlaid (~40.2 MB)
    float* ws = (float*)d_ws;
    ushort_t* wbf     = (ushort_t*)ws;
    ushort_t* w2_enc0 = wbf + 147456;
    ushort_t* w2_enc1 = w2_enc0 + 294912;
    ushort_t* w2_dec0 = w2_enc1 + 147456;
    ushort_t* w2_dec1 = w2_dec0 + 36864;
    ushort_t* w2_est  = w2_dec1 + 36864;          // ends at 350208 floats
    float* U1      = ws + 350208;                 // 1048576
    float* u0      = U1 + 1048576;                // 1048576
    float* e1      = u0 + 1048576;                // 1048576
    float* partML  = e1 + 1048576;                // 262144
    float* regPart = partML + 262144;             // 2097152 (attn0 partO | est)
    float* regMot  = regPart + 2097152;           // 4194304 (conv partials | attn1 partO | mot | xT)

    float* e0 = U1;
    ushort_t* thT0 = (ushort_t*)(U1 + 262144);
    ushort_t* phT0 = thT0 + 131072;
    ushort_t* gT0  = phT0 + 131072;
    float* m0 = U1 + 458752;
    ushort_t* thT1 = (ushort_t*)U1;
    ushort_t* phT1 = thT1 + 524288;
    ushort_t* gT1  = phT1 + 524288;
    float* m1  = U1;
    float* mot = regMot;
    ushort_t* xTb = (ushort_t*)regMot;
    float* est = regPart;
    float* partO1 = regMot;

    float* out = (float*)d_out;
    const size_t frame  = (size_t)2 * 128 * 128 * 128;
    const size_t cframe = (size_t)2 * 256 * 64 * 64;

    hipMemcpyAsync(out, x_all, frame * sizeof(float), hipMemcpyDeviceToDevice, stream);

    // ---- one-time weight prep
    castw_perm_kernel<<<(147456 + 255) / 256, 256, 0, stream>>>(dcn_w, wbf);
    castw2_kernel<<<(64 * 4608 + 255) / 256, 256, 0, stream>>>(enc_w0, w2_enc0, 64, 512, 4608, 0);
    castw2_kernel<<<(64 * 2304 + 255) / 256, 256, 0, stream>>>(enc_w1, w2_enc1, 64, 256, 2304, 0);
    castw2_kernel<<<(64 * 576 + 255) / 256, 256, 0, stream>>>(dec_w0, w2_dec0, 64, 64, 576, 1);
    castw2_kernel<<<(64 * 576 + 255) / 256, 256, 0, stream>>>(dec_w1, w2_dec1, 64, 64, 576, 1);
    castw2_kernel<<<(64 * 576 + 255) / 256, 256, 0, stream>>>(off_w, w2_est, 27, 64, 576, 0);

    // ==== batched motion pipeline ====

    // e0 = lrelu(conv3x3 s2 (pc||cc; 512->64)) : [4][64][1024]   (ksplit 16)
    conv3x3_mfma<2, 0><<<4 * 16 * 16, 256, 0, stream>>>(
        ms_coarse + cframe, ms_coarse, 256, cframe, 64, 64, 512,
        w2_enc0, 4608, 32, 1024, 16, 16, 9, regMot, nullptr, 0, 0, nullptr);
    reduce_bias_act<<<1024, 256, 0, stream>>>(regMot, enc_b0, e0, 64, 1024, 16, 1);

    // non-local 0 (N=1024, KVS=16)
    conv1x1x3_bf16<<<48, 256, 0, stream>>>(e0, 1024,
        nl_tw[0], nl_tb[0], nl_pw[0], nl_pb[0], nl_gw[0], nl_gb[0], thT0, phT0, gT0);
    attn_flash<<<4 * 16 * 16, 256, 0, stream>>>(thT0, phT0, gT0, regPart, partML, 1024, 16);
    nl_merge_fused<<<64, 256, 0, stream>>>(e0, regPart, partML, nullptr,
        nl_ww[0], nl_wb[0], m0, 1024, 16);

    // u0 = lrelu(deconv(m0)) : [4][64][4096]   (ksplit 3)
    conv3x3_mfma<1, 1><<<4 * 64 * 3, 256, 0, stream>>>(
        m0, m0, 64, (size_t)2 * 64 * 1024, 32, 32, 64,
        w2_dec0, 576, 64, 4096, 64, 3, 6, regMot, nullptr, 0, 0, nullptr);
    reduce_bias_act<<<4096, 256, 0, stream>>>(regMot, dec_b0, u0, 64, 4096, 3, 1);

    // e1 = lrelu(conv3x3 s2 (pf||cf; 256->64)) : [4][64][4096]   (ksplit 4)
    conv3x3_mfma<2, 0><<<4 * 64 * 4, 256, 0, stream>>>(
        ms_fine + frame, ms_fine, 128, frame, 128, 128, 256,
        w2_enc1, 2304, 64, 4096, 64, 4, 18, regMot, nullptr, 0, 0, nullptr);
    reduce_bias_act<<<4096, 256, 0, stream>>>(regMot, enc_b1, e1, 64, 4096, 4, 1);

    // non-local 1 (N=4096, KVS=8, partO in regMot)
    conv1x1x3_bf16<<<192, 256, 0, stream>>>(e1, 4096,
        nl_tw[1], nl_tb[1], nl_pw[1], nl_pb[1], nl_gw[1], nl_gb[1], thT1, phT1, gT1);
    attn_flash<<<4 * 64 * 8, 256, 0, stream>>>(thT1, phT1, gT1, partO1, partML, 4096, 8);
    nl_merge_fused<<<256, 256, 0, stream>>>(e1, partO1, partML, u0,
        nl_ww[1], nl_wb[1], m1, 4096, 8);

    // mot = lrelu(deconv(m1)) : [4][64][16384]  (fused epilogue)
    conv3x3_mfma<1, 1><<<4 * 256, 256, 0, stream>>>(
        m1, m1, 64, (size_t)2 * 64 * 4096, 64, 64, 64,
        w2_dec1, 576, 128, 16384, 256, 1, 18, regPart, dec_b1, 1, 64, mot);

    // est = conv3x3 s1 (mot; 64->27) : [4][27][16384]  (fused epilogue)
    conv3x3_mfma<1, 0><<<4 * 256, 256, 0, stream>>>(
        mot, mot, 64, (size_t)2 * 64 * 16384, 128, 128, 64,
        w2_est, 576, 128, 16384, 256, 1, 18, regPart, off_b, 0, 27, est);

    // ==== batched transpose (bf16) + batched deformable conv ====
    transpose_nhwc_bf16<<<8192, 256, 0, stream>>>(x_all, xTb);
    deform_mfma5<<<1024, 256, 0, stream>>>(xTb, est, wbf, dcn_b, out);
}

// Round 13
// 361.150 us; speedup vs baseline: 1.1964x; 1.1964x over previous
//
#include <hip/hip_runtime.h>
#include <math.h>

typedef __attribute__((ext_vector_type(8))) short bf16x8;
typedef __attribute__((ext_vector_type(4))) float f32x4;
typedef unsigned short ushort_t;
typedef unsigned int uint_t;

__device__ __forceinline__ float lrelu_f(float x) { return x >= 0.f ? x : 0.01f * x; }

__device__ __forceinline__ ushort_t f2bf(float f) {
    uint_t x = __float_as_uint(f);
    uint_t r = (x + 0x7fffu + ((x >> 16) & 1u)) >> 16;
    return (ushort_t)r;
}

__device__ __forceinline__ uint_t pack_bf16(float lo, float hi) {
    uint_t out;
    asm("v_cvt_pk_bf16_f32 %0, %1, %2" : "=v"(out) : "v"(lo), "v"(hi));
    return out;
}

__device__ __forceinline__ float fexp2(float x) {
    float r;
    asm("v_exp_f32 %0, %1" : "=v"(r) : "v"(x));
    return r;
}

// ===========================================================================
// Weight prep: w2[co64][K'] bf16, channel-block-major K ordering.
// ===========================================================================
__global__ __launch_bounds__(256) void castw2_kernel(const float* __restrict__ w,
    ushort_t* __restrict__ w2, int Cout, int Cin, int K, int deconv)
{
    int idx = blockIdx.x * 256 + threadIdx.x;
    if (idx >= 64 * K) return;
    int co = idx / K, kp = idx % K;
    int cb = kp / 288;
    int r  = kp % 288;
    int tap = r >> 5, cl = r & 31;
    int ci = cb * 32 + cl;
    float val = 0.f;
    if (co < Cout)
        val = deconv ? w[(size_t)(ci * Cout + co) * 9 + (8 - tap)]
                     : w[(size_t)(co * Cin + ci) * 9 + tap];
    w2[idx] = f2bf(val);
}

// ===========================================================================
// bf16 MFMA implicit-GEMM 3x3 conv over 4-batch (round-11 version).
// ===========================================================================
template<int STRIDE, int MODE>
__global__ __launch_bounds__(256) void conv3x3_mfma(
    const float* __restrict__ inA, const float* __restrict__ inB, int CinA,
    size_t sStrideA, int Hin, int Win, int Cin,
    const ushort_t* __restrict__ w2, int K,
    int Wout, int Npx, int tilesPerMap, int ksplit, int chunksPerKs,
    float* __restrict__ part,
    const float* __restrict__ bias, int act, int CoutStore, float* __restrict__ outDirect)
{
    __shared__ ushort_t sB[64 * 40];
    int tile = blockIdx.x % tilesPerMap;
    int ks   = (blockIdx.x / tilesPerMap) % ksplit;
    int b4   = blockIdx.x / (tilesPerMap * ksplit);
    int s_idx = b4 >> 1, bb = b4 & 1;
    int tid  = threadIdx.x;
    int wave = tid >> 6, lane = tid & 63;
    int lrow = lane & 15, lkg = lane >> 4;
    int px  = tid & 63;
    int cio = wave * 8;
    int p   = tile * 64 + px;
    int oy  = p / Wout, ox = p - oy * Wout;
    int HWin = Hin * Win;
    int CinB = Cin - CinA;

    f32x4 acc[4];
    #pragma unroll
    for (int n2 = 0; n2 < 4; ++n2) acc[n2] = (f32x4){0.f, 0.f, 0.f, 0.f};

    for (int cch = 0; cch < chunksPerKs; ++cch) {
        int chunkIdx = ks * chunksPerKs + cch;
        int cb  = chunkIdx / 9;
        int tap = chunkIdx - cb * 9;
        int cib = cb * 32;
        int ky = tap / 3, kx = tap - ky * 3;
        float msk;
        int offp;
        if (MODE == 0) {
            int iy = oy * STRIDE - 1 + ky;
            int ix = ox * STRIDE - 1 + kx;
            bool vld = (iy >= 0) && (iy < Hin) && (ix >= 0) && (ix < Win);
            msk = vld ? 1.f : 0.f;
            offp = min(max(iy, 0), Hin - 1) * Win + min(max(ix, 0), Win - 1);
        } else {
            int uy = oy + ky, ux = ox + kx;
            int r = (uy - 1) >> 1, q = (ux - 1) >> 1;
            bool vld = (uy & 1) && (ux & 1) && (r < Hin) && (q < Win);
            msk = vld ? 1.f : 0.f;
            offp = min(max(r, 0), Hin - 1) * Win + min(max(q, 0), Win - 1);
        }
        int c = cib + cio;
        const float* src = (c < CinA)
            ? inA + s_idx * sStrideA + (size_t)(bb * CinA + c) * HWin
            : inB + (size_t)(bb * CinB + (c - CinA)) * HWin;
        float v[8];
        #pragma unroll
        for (int j = 0; j < 8; ++j) v[j] = src[(size_t)j * HWin + offp] * msk;
        uint4 pk;
        pk.x = pack_bf16(v[0], v[1]);
        pk.y = pack_bf16(v[2], v[3]);
        pk.z = pack_bf16(v[4], v[5]);
        pk.w = pack_bf16(v[6], v[7]);
        __syncthreads();
        *(uint4*)&sB[px * 40 + cio] = pk;
        __syncthreads();

        const ushort_t* wr = w2 + (size_t)(wave * 16 + lrow) * K + chunkIdx * 32 + lkg * 8;
        bf16x8 afr = *(const bf16x8*)wr;
        #pragma unroll
        for (int n2 = 0; n2 < 4; ++n2) {
            bf16x8 bfr = *(const bf16x8*)&sB[(n2 * 16 + lrow) * 40 + lkg * 8];
            acc[n2] = __builtin_amdgcn_mfma_f32_16x16x32_bf16(afr, bfr, acc[n2], 0, 0, 0);
        }
    }

    if (bias) {
        #pragma unroll
        for (int n2 = 0; n2 < 4; ++n2) {
            #pragma unroll
            for (int j = 0; j < 4; ++j) {
                int co = wave * 16 + lkg * 4 + j;
                if (co < CoutStore) {
                    int pp = tile * 64 + n2 * 16 + lrow;
                    float r = acc[n2][j] + bias[co];
                    if (act) r = lrelu_f(r);
                    outDirect[((size_t)(b4 * CoutStore + co)) * (size_t)Npx + pp] = r;
                }
            }
        }
    } else {
        #pragma unroll
        for (int n2 = 0; n2 < 4; ++n2) {
            #pragma unroll
            for (int j = 0; j < 4; ++j) {
                int co = wave * 16 + lkg * 4 + j;
                int pp = tile * 64 + n2 * 16 + lrow;
                part[((size_t)(ks * 4 + b4) * 64 + co) * (size_t)Npx + pp] = acc[n2][j];
            }
        }
    }
}

__global__ __launch_bounds__(256) void reduce_bias_act(const float* __restrict__ part,
    const float* __restrict__ bias, float* __restrict__ out,
    int Cout, int Npx, int ksplit, int act)
{
    int idx = blockIdx.x * 256 + threadIdx.x;
    int total = 4 * Cout * Npx;
    if (idx >= total) return;
    int p  = idx % Npx;
    int co = (idx / Npx) % Cout;
    int b4 = idx / (Npx * Cout);
    float s = bias[co];
    for (int ks = 0; ks < ksplit; ++ks)
        s += part[(((size_t)ks * 4 + b4) * 64 + co) * (size_t)Npx + p];
    if (act) s = lrelu_f(s);
    out[((size_t)b4 * Cout + co) * (size_t)Npx + p] = s;
}

__global__ __launch_bounds__(256) void castw_perm_kernel(const float* __restrict__ w,
    ushort_t* __restrict__ wbf)
{
    int idx = blockIdx.x * 256 + threadIdx.x;
    if (idx >= 147456) return;
    int co = idx / 1152;
    int r  = idx % 1152;
    int chunk = r / 288;
    int r2 = r % 288;
    int tap = r2 >> 5;
    int cl  = r2 & 31;
    int ci = chunk * 32 + cl;
    wbf[idx] = f2bf(w[(size_t)co * 1152 + ci * 9 + tap]);
}

// Batched NCHW frames (s=1,2) -> NHWC bf16 [b4][16384][128]
__global__ __launch_bounds__(256) void transpose_nhwc_bf16(const float* __restrict__ x,
    ushort_t* __restrict__ xT)
{
    __shared__ float t[32][33];
    int cT = blockIdx.x & 3;
    int pT = (blockIdx.x >> 2) & 511;
    int b4 = blockIdx.x >> 11;
    int tx = threadIdx.x & 31, ty = threadIdx.x >> 5;
    const float* src = x + ((size_t)((b4 + 2) * 128) + cT * 32) * 16384 + (size_t)pT * 32;
    #pragma unroll
    for (int i = 0; i < 4; ++i)
        t[ty + 8 * i][tx] = src[(size_t)(ty + 8 * i) * 16384 + tx];
    __syncthreads();
    ushort_t* dst = xT + ((size_t)b4 * 16384 + (size_t)pT * 32) * 128 + cT * 32;
    #pragma unroll
    for (int i = 0; i < 4; ++i)
        dst[(size_t)(ty + 8 * i) * 128 + tx] = f2bf(t[tx][ty + 8 * i]);
}

// ---------------------------------------------------------------------------
// Fused 1x1 convs -> bf16 attention operands, 4-batch (thT pre-scaled log2e).
// ---------------------------------------------------------------------------
__global__ __launch_bounds__(256) void conv1x1x3_bf16(const float* __restrict__ e, int N,
    const float* __restrict__ tw, const float* __restrict__ tb,
    const float* __restrict__ pw, const float* __restrict__ pb,
    const float* __restrict__ gw, const float* __restrict__ gb,
    ushort_t* __restrict__ thT, ushort_t* __restrict__ phT, ushort_t* __restrict__ gT)
{
    __shared__ float sw[32 * 64];
    __shared__ float sb[32];
    int tid = threadIdx.x;
    int idx = blockIdx.x * 256 + tid;
    int j = idx / (4 * N);
    const float* wsel = (j == 0) ? tw : (j == 1) ? pw : gw;
    const float* bsel = (j == 0) ? tb : (j == 1) ? pb : gb;
    for (int i = tid; i < 2048; i += 256) sw[i] = wsel[i];
    if (tid < 32) sb[tid] = bsel[tid];
    __syncthreads();
    int rem = idx - j * 4 * N;
    int n = rem % N, b4 = rem / N;
    float ein[64];
    const float* ep = e + (size_t)b4 * 64 * N + n;
    #pragma unroll
    for (int ci = 0; ci < 64; ++ci) ein[ci] = ep[(size_t)ci * N];

    float val[32];
    #pragma unroll
    for (int cc = 0; cc < 32; ++cc) {
        float acc = sb[cc];
        const float* wr = &sw[cc * 64];
        #pragma unroll
        for (int ci = 0; ci < 64; ++ci) acc = fmaf(wr[ci], ein[ci], acc);
        val[cc] = acc;
    }
    if (j == 0) {
        #pragma unroll
        for (int cc = 0; cc < 32; ++cc) val[cc] *= 1.44269504f;
    }
    if (j < 2) {
        ushort_t* row = (j == 0 ? thT : phT) + ((size_t)b4 * N + n) * 32;
        #pragma unroll
        for (int w4 = 0; w4 < 4; ++w4) {
            uint4 pk;
            pk.x = pack_bf16(val[8 * w4 + 0], val[8 * w4 + 1]);
            pk.y = pack_bf16(val[8 * w4 + 2], val[8 * w4 + 3]);
            pk.z = pack_bf16(val[8 * w4 + 4], val[8 * w4 + 5]);
            pk.w = pack_bf16(val[8 * w4 + 6], val[8 * w4 + 7]);
            *(uint4*)(row + 8 * w4) = pk;
        }
    } else {
        #pragma unroll
        for (int cc = 0; cc < 32; ++cc)
            gT[((size_t)b4 * 32 + cc) * N + n] = f2bf(val[cc]);
    }
}

// ===========================================================================
// Flash split-K MFMA attention (exp2 domain, defer-max), 4-batch.
// ===========================================================================
__global__ __launch_bounds__(256) void attn_flash(const ushort_t* __restrict__ thT,
    const ushort_t* __restrict__ phT, const ushort_t* __restrict__ gT,
    float* __restrict__ partO, float* __restrict__ partML, int N, int KVS)
{
    __shared__ ushort_t sP[4][16 * 40];
    int tid  = threadIdx.x;
    int wave = tid >> 6, lane = tid & 63;
    int lq = lane & 15, lkg = lane >> 4;
    int nqb = N / 64;
    int ks = blockIdx.x % KVS;
    int qb = (blockIdx.x / KVS) % nqb;
    int b4 = blockIdx.x / (KVS * nqb);
    int q0w = qb * 64 + wave * 16;
    int chunk = N / KVS;
    int m_start = ks * chunk;

    bf16x8 qf = *(const bf16x8*)(thT + ((size_t)b4 * N + q0w + lq) * 32 + 8 * lkg);

    float m_run = -1e30f, l_run = 0.f;
    f32x4 acc[2];
    acc[0] = (f32x4){0.f, 0.f, 0.f, 0.f};
    acc[1] = (f32x4){0.f, 0.f, 0.f, 0.f};

    for (int m0 = m_start; m0 < m_start + chunk; m0 += 64) {
        f32x4 tf[4];
        #pragma unroll
        for (int f = 0; f < 4; ++f) {
            bf16x8 kf = *(const bf16x8*)(phT + ((size_t)b4 * N + m0 + f * 16 + lq) * 32 + 8 * lkg);
            tf[f] = __builtin_amdgcn_mfma_f32_16x16x32_bf16(kf, qf,
                        (f32x4){0.f, 0.f, 0.f, 0.f}, 0, 0, 0);
        }

        float mx = -1e30f;
        #pragma unroll
        for (int f = 0; f < 4; ++f)
            #pragma unroll
            for (int r = 0; r < 4; ++r) mx = fmaxf(mx, tf[f][r]);
        mx = fmaxf(mx, __shfl_xor(mx, 16));
        mx = fmaxf(mx, __shfl_xor(mx, 32));

        if (__any(mx > m_run)) {
            float m_new = fmaxf(m_run, mx);
            float scale = fexp2(m_run - m_new);
            l_run *= scale;
            m_run = m_new;
            float sc[4];
            #pragma unroll
            for (int r = 0; r < 4; ++r) sc[r] = __shfl(scale, 4 * lkg + r);
            #pragma unroll
            for (int h = 0; h < 2; ++h)
                #pragma unroll
                for (int r = 0; r < 4; ++r) acc[h][r] *= sc[r];
        }

        float rs = 0.f;
        #pragma unroll
        for (int f = 0; f < 4; ++f)
            #pragma unroll
            for (int r = 0; r < 4; ++r) {
                float pv = fexp2(tf[f][r] - m_run);
                tf[f][r] = pv;
                rs += pv;
            }
        rs += __shfl_xor(rs, 16);
        rs += __shfl_xor(rs, 32);
        l_run += rs;

        #pragma unroll
        for (int f = 0; f < 4; ++f) {
            *(uint_t*)&sP[wave][lq * 40 + f * 16 + 4 * lkg]     = pack_bf16(tf[f][0], tf[f][1]);
            *(uint_t*)&sP[wave][lq * 40 + f * 16 + 4 * lkg + 2] = pack_bf16(tf[f][2], tf[f][3]);
        }

        #pragma unroll
        for (int mc = 0; mc < 2; ++mc) {
            bf16x8 pf = *(const bf16x8*)&sP[wave][lq * 40 + mc * 32 + 8 * lkg];
            #pragma unroll
            for (int h = 0; h < 2; ++h) {
                bf16x8 vf = *(const bf16x8*)(gT + ((size_t)b4 * 32 + h * 16 + lq) * N
                                             + m0 + mc * 32 + 8 * lkg);
                acc[h] = __builtin_amdgcn_mfma_f32_16x16x32_bf16(pf, vf, acc[h], 0, 0, 0);
            }
        }
    }

    #pragma unroll
    for (int h = 0; h < 2; ++h) {
        #pragma unroll
        for (int r = 0; r < 4; ++r) {
            int q = q0w + 4 * lkg + r;
            partO[(((size_t)ks * 4 + b4) * N + q) * 32 + h * 16 + lq] = acc[h][r];
        }
    }
    if (lane < 16) {
        size_t mlo = (((size_t)ks * 4 + b4) * N + q0w + lq) * 2;
        partML[mlo]     = m_run;
        partML[mlo + 1] = l_run;
    }
}

// ===========================================================================
// Fused flash-combine (exp2 domain) + non-local merge (4-batch).
// ===========================================================================
__global__ __launch_bounds__(256) void nl_merge_fused(const float* __restrict__ e,
    const float* __restrict__ partO, const float* __restrict__ partML,
    const float* __restrict__ u,
    const float* __restrict__ ww, const float* __restrict__ wb,
    float* __restrict__ out, int N, int KVS)
{
    __shared__ float sw[64 * 32];
    __shared__ float sb[64];
    int tid = threadIdx.x;
    for (int i = tid; i < 2048; i += 256) sw[i] = ww[i];
    if (tid < 64) sb[tid] = wb[tid];
    __syncthreads();
    int idx = blockIdx.x * 256 + tid;
    int n = idx % N;
    int cog = (idx / N) & 3;
    int b4 = idx / (4 * N);

    float mstar = -1e30f;
    for (int ks = 0; ks < KVS; ++ks)
        mstar = fmaxf(mstar, partML[(((size_t)ks * 4 + b4) * N + n) * 2]);
    float denom = 0.f;
    float yv[32];
    #pragma unroll
    for (int c = 0; c < 32; ++c) yv[c] = 0.f;
    for (int ks = 0; ks < KVS; ++ks) {
        size_t mlo = (((size_t)ks * 4 + b4) * N + n) * 2;
        float w = fexp2(partML[mlo] - mstar);
        denom += w * partML[mlo + 1];
        const f32x4* op = (const f32x4*)(partO + (((size_t)ks * 4 + b4) * N + n) * 32);
        #pragma unroll
        for (int jj = 0; jj < 8; ++jj) {
            f32x4 v = op[jj];
            #pragma unroll
            for (int t = 0; t < 4; ++t) yv[4 * jj + t] = fmaf(w, v[t], yv[4 * jj + t]);
        }
    }
    float inv = 1.f / denom;
    #pragma unroll
    for (int i = 0; i < 16; ++i) {
        int co = cog * 16 + i;
        float dot = 0.f;
        const float* wr = &sw[co * 32];
        #pragma unroll
        for (int c = 0; c < 32; ++c) dot = fmaf(wr[c], yv[c], dot);
        size_t o = (size_t)b4 * 64 * N + (size_t)co * N + n;
        float r = sb[co] + inv * dot + 2.f * e[o];
        if (u) r += u[o];
        out[o] = r;
    }
}

// ===========================================================================
// Deformable conv v6: 512 threads / 8 waves per block (wave owns 16 co ->
// acc 16 VGPR), sampling params in LDS tables, bf16 NHWC 8-ch gathers.
// LDS 51.7KB -> 3 blocks/CU but 24 waves/CU (vs 12 in v4).
// ===========================================================================
__global__ __launch_bounds__(512, 6) void deform_mfma6(const ushort_t* __restrict__ xT,
    const float* __restrict__ est, const ushort_t* __restrict__ wbf,
    const float* __restrict__ bias, float* __restrict__ out)
{
    const int H = 128, W = 128, HW = 16384;
    const int BS = 296;
    __shared__ ushort_t sB[64 * BS];
    __shared__ float4 sW[576];
    __shared__ uint2  sO[576];
    int id  = blockIdx.x;                       // 1024 blocks, %8==0
    int lin = (id & 7) * 128 + (id >> 3);       // XCD-chunked bijective remap
    int tile = lin & 255;
    int b4   = lin >> 8;                        // 0..3, image = b4+2
    int p0   = tile * 64;
    int tid  = threadIdx.x;

    const float* eb = est + (size_t)b4 * 27 * HW;
    for (int i = tid; i < 576; i += 512) {
        int k = i >> 6, j = i & 63;
        int p = p0 + j;
        int yy = p >> 7, xx = p & 127;
        float oy = eb[(size_t)(9 + 2 * k) * HW + p];
        float ox = eb[(size_t)(10 + 2 * k) * HW + p];
        float mv = eb[(size_t)k * HW + p];
        float mk = 1.f / (1.f + __expf(-mv));
        float py = (float)(yy + (k / 3) - 1) + oy;
        float qx = (float)(xx + (k % 3) - 1) + ox;
        float fy0 = floorf(py), fx0 = floorf(qx);
        float wy = py - fy0, wx = qx - fx0;
        int y0 = (int)fy0, x0 = (int)fx0;
        int y1 = y0 + 1, x1 = x0 + 1;
        bool yv0 = (y0 >= 0) && (y0 < H), yv1 = (y1 >= 0) && (y1 < H);
        bool xv0 = (x0 >= 0) && (x0 < W), xv1 = (x1 >= 0) && (x1 < W);
        int y0c = min(max(y0, 0), H - 1), y1c = min(max(y1, 0), H - 1);
        int x0c = min(max(x0, 0), W - 1), x1c = min(max(x1, 0), W - 1);
        float4 w4;
        w4.x = (yv0 && xv0) ? (1.f - wy) * (1.f - wx) * mk : 0.f;
        w4.y = (yv0 && xv1) ? (1.f - wy) * wx * mk : 0.f;
        w4.z = (yv1 && xv0) ? wy * (1.f - wx) * mk : 0.f;
        w4.w = (yv1 && xv1) ? wy * wx * mk : 0.f;
        sW[i] = w4;
        uint_t o00 = (uint_t)(y0c * W + x0c), o01 = (uint_t)(y0c * W + x1c);
        uint_t o10 = (uint_t)(y1c * W + x0c), o11 = (uint_t)(y1c * W + x1c);
        sO[i] = (uint2){ o00 | (o01 << 16), o10 | (o11 << 16) };
    }

    int wave = tid >> 6, lane = tid & 63;
    int co_base = wave * 16;                    // 8 waves x 16 co = 128
    int lrow = lane & 15, lkg = lane >> 4;
    int cg = tid & 3;

    f32x4 acc[4];
    #pragma unroll
    for (int n2 = 0; n2 < 4; ++n2) acc[n2] = (f32x4){0.f, 0.f, 0.f, 0.f};

    const ushort_t* xb = xT + (size_t)b4 * HW * 128;

    for (int cc = 0; cc < 128; cc += 32) {
        __syncthreads();
        #pragma unroll
        for (int it = 0; it < 5; ++it) {
            int task = it * 512 + tid;
            if (task < 2304) {
                int si = task >> 2;
                float4 w4 = sW[si];
                uint2 o4 = sO[si];
                int chb = cc + cg * 8;
                uint4 u00 = *(const uint4*)(xb + (size_t)(o4.x & 0xFFFFu) * 128 + chb);
                uint4 u01 = *(const uint4*)(xb + (size_t)(o4.x >> 16) * 128 + chb);
                uint4 u10 = *(const uint4*)(xb + (size_t)(o4.y & 0xFFFFu) * 128 + chb);
                uint4 u11 = *(const uint4*)(xb + (size_t)(o4.y >> 16) * 128 + chb);
                float v[8];
                const uint_t* a0 = (const uint_t*)&u00;
                const uint_t* a1 = (const uint_t*)&u01;
                const uint_t* a2 = (const uint_t*)&u10;
                const uint_t* a3 = (const uint_t*)&u11;
                #pragma unroll
                for (int q = 0; q < 4; ++q) {
                    float c00l = __uint_as_float(a0[q] << 16), c00h = __uint_as_float(a0[q] & 0xffff0000u);
                    float c01l = __uint_as_float(a1[q] << 16), c01h = __uint_as_float(a1[q] & 0xffff0000u);
                    float c10l = __uint_as_float(a2[q] << 16), c10h = __uint_as_float(a2[q] & 0xffff0000u);
                    float c11l = __uint_as_float(a3[q] << 16), c11h = __uint_as_float(a3[q] & 0xffff0000u);
                    v[2 * q]     = w4.x * c00l + w4.y * c01l + w4.z * c10l + w4.w * c11l;
                    v[2 * q + 1] = w4.x * c00h + w4.y * c01h + w4.z * c10h + w4.w * c11h;
                }
                int pxl = si & 63, tap = si >> 6;
                uint4 pk;
                pk.x = pack_bf16(v[0], v[1]);
                pk.y = pack_bf16(v[2], v[3]);
                pk.z = pack_bf16(v[4], v[5]);
                pk.w = pack_bf16(v[6], v[7]);
                *(uint4*)&sB[pxl * BS + tap * 32 + cg * 8] = pk;
            }
        }
        __syncthreads();
        int kbase = cc * 9;
        #pragma unroll
        for (int ks = 0; ks < 9; ++ks) {
            bf16x8 afr = *reinterpret_cast<const bf16x8*>(
                wbf + (size_t)(co_base + lrow) * 1152 + kbase + ks * 32 + lkg * 8);
            #pragma unroll
            for (int n2 = 0; n2 < 4; ++n2) {
                bf16x8 bfr = *reinterpret_cast<const bf16x8*>(
                    &sB[(n2 * 16 + lrow) * BS + ks * 32 + lkg * 8]);
                acc[n2] = __builtin_amdgcn_mfma_f32_16x16x32_bf16(afr, bfr, acc[n2], 0, 0, 0);
            }
        }
    }

    #pragma unroll
    for (int j = 0; j < 4; ++j) {
        int co = co_base + lkg * 4 + j;
        float bb = bias[co];
        #pragma unroll
        for (int n2 = 0; n2 < 4; ++n2) {
            int px = p0 + n2 * 16 + lrow;
            out[((size_t)((b4 + 2) * 128 + co)) * HW + px] = acc[n2][j] + bb;
        }
    }
}

extern "C" void kernel_launch(void* const* d_in, const int* in_sizes, int n_in,
                              void* d_out, int out_size, void* d_ws, size_t ws_size,
                              hipStream_t stream)
{
    const float* x_all     = (const float*)d_in[0];
    const float* ms_fine   = (const float*)d_in[1];
    const float* ms_coarse = (const float*)d_in[2];
    const float* enc_w0 = (const float*)d_in[3];
    const float* enc_b0 = (const float*)d_in[4];
    const float* enc_w1 = (const float*)d_in[5];
    const float* enc_b1 = (const float*)d_in[6];
    const float* nl_tw[2] = { (const float*)d_in[7],  (const float*)d_in[15] };
    const float* nl_tb[2] = { (const float*)d_in[8],  (const float*)d_in[16] };
    const float* nl_pw[2] = { (const float*)d_in[9],  (const float*)d_in[17] };
    const float* nl_pb[2] = { (const float*)d_in[10], (const float*)d_in[18] };
    const float* nl_gw[2] = { (const float*)d_in[11], (const float*)d_in[19] };
    const float* nl_gb[2] = { (const float*)d_in[12], (const float*)d_in[20] };
    const float* nl_ww[2] = { (const float*)d_in[13], (const float*)d_in[21] };
    const float* nl_wb[2] = { (const float*)d_in[14], (const float*)d_in[22] };
    const float* dec_w0 = (const float*)d_in[23];
    const float* dec_b0 = (const float*)d_in[24];
    const float* dec_w1 = (const float*)d_in[25];
    const float* dec_b1 = (const float*)d_in[26];
    const float* off_w  = (const float*)d_in[27];
    const float* off_b  = (const float*)d_in[28];
    const float* dcn_w  = (const float*)d_in[29];
    const float* dcn_b  = (const float*)d_in[30];

    // ---- workspace layout (floats), lifetime-overlaid (~40.2 MB)
    float* ws = (float*)d_ws;
    ushort_t* wbf     = (ushort_t*)ws;
    ushort_t* w2_enc0 = wbf + 147456;
    ushort_t* w2_enc1 = w2_enc0 + 294912;
    ushort_t* w2_dec0 = w2_enc1 + 147456;
    ushort_t* w2_dec1 = w2_dec0 + 36864;
    ushort_t* w2_est  = w2_dec1 + 36864;          // ends at 350208 floats
    float* U1      = ws + 350208;                 // 1048576
    float* u0      = U1 + 1048576;                // 1048576
    float* e1      = u0 + 1048576;                // 1048576
    float* partML  = e1 + 1048576;                // 262144
    float* regPart = partML + 262144;             // 2097152 (conv partials | attn0 partO | est)
    float* regMot  = regPart + 2097152;           // 4194304 (attn1 partO | mot | xT bf16)

    float* e0 = U1;
    ushort_t* thT0 = (ushort_t*)(U1 + 262144);
    ushort_t* phT0 = thT0 + 131072;
    ushort_t* gT0  = phT0 + 131072;
    float* m0 = U1 + 458752;
    ushort_t* thT1 = (ushort_t*)U1;
    ushort_t* phT1 = thT1 + 524288;
    ushort_t* gT1  = phT1 + 524288;
    float* m1  = U1;
    float* mot = regMot;
    ushort_t* xTb = (ushort_t*)regMot;
    float* est = regPart;
    float* partO1 = regMot;

    float* out = (float*)d_out;
    const size_t frame  = (size_t)2 * 128 * 128 * 128;
    const size_t cframe = (size_t)2 * 256 * 64 * 64;

    hipMemcpyAsync(out, x_all, frame * sizeof(float), hipMemcpyDeviceToDevice, stream);

    // ---- one-time weight prep
    castw_perm_kernel<<<(147456 + 255) / 256, 256, 0, stream>>>(dcn_w, wbf);
    castw2_kernel<<<(64 * 4608 + 255) / 256, 256, 0, stream>>>(enc_w0, w2_enc0, 64, 512, 4608, 0);
    castw2_kernel<<<(64 * 2304 + 255) / 256, 256, 0, stream>>>(enc_w1, w2_enc1, 64, 256, 2304, 0);
    castw2_kernel<<<(64 * 576 + 255) / 256, 256, 0, stream>>>(dec_w0, w2_dec0, 64, 64, 576, 1);
    castw2_kernel<<<(64 * 576 + 255) / 256, 256, 0, stream>>>(dec_w1, w2_dec1, 64, 64, 576, 1);
    castw2_kernel<<<(64 * 576 + 255) / 256, 256, 0, stream>>>(off_w, w2_est, 27, 64, 576, 0);

    // ==== batched motion pipeline ====

    // e0 = lrelu(conv3x3 s2 (pc||cc; 512->64)) : [4][64][1024]
    conv3x3_mfma<2, 0><<<4 * 16 * 8, 256, 0, stream>>>(
        ms_coarse + cframe, ms_coarse, 256, cframe, 64, 64, 512,
        w2_enc0, 4608, 32, 1024, 16, 8, 18, regPart, nullptr, 0, 0, nullptr);
    reduce_bias_act<<<1024, 256, 0, stream>>>(regPart, enc_b0, e0, 64, 1024, 8, 1);

    // non-local 0 (N=1024, KVS=8)
    conv1x1x3_bf16<<<48, 256, 0, stream>>>(e0, 1024,
        nl_tw[0], nl_tb[0], nl_pw[0], nl_pb[0], nl_gw[0], nl_gb[0], thT0, phT0, gT0);
    attn_flash<<<4 * 16 * 8, 256, 0, stream>>>(thT0, phT0, gT0, regPart, partML, 1024, 8);
    nl_merge_fused<<<64, 256, 0, stream>>>(e0, regPart, partML, nullptr,
        nl_ww[0], nl_wb[0], m0, 1024, 8);

    // u0 = lrelu(deconv(m0)) : [4][64][4096]
    conv3x3_mfma<1, 1><<<4 * 64 * 2, 256, 0, stream>>>(
        m0, m0, 64, (size_t)2 * 64 * 1024, 32, 32, 64,
        w2_dec0, 576, 64, 4096, 64, 2, 9, regPart, nullptr, 0, 0, nullptr);
    reduce_bias_act<<<4096, 256, 0, stream>>>(regPart, dec_b0, u0, 64, 4096, 2, 1);

    // e1 = lrelu(conv3x3 s2 (pf||cf; 256->64)) : [4][64][4096]
    conv3x3_mfma<2, 0><<<4 * 64 * 2, 256, 0, stream>>>(
        ms_fine + frame, ms_fine, 128, frame, 128, 128, 256,
        w2_enc1, 2304, 64, 4096, 64, 2, 36, regPart, nullptr, 0, 0, nullptr);
    reduce_bias_act<<<4096, 256, 0, stream>>>(regPart, enc_b1, e1, 64, 4096, 2, 1);

    // non-local 1 (N=4096, KVS=8, partO in regMot)
    conv1x1x3_bf16<<<192, 256, 0, stream>>>(e1, 4096,
        nl_tw[1], nl_tb[1], nl_pw[1], nl_pb[1], nl_gw[1], nl_gb[1], thT1, phT1, gT1);
    attn_flash<<<4 * 64 * 8, 256, 0, stream>>>(thT1, phT1, gT1, partO1, partML, 4096, 8);
    nl_merge_fused<<<256, 256, 0, stream>>>(e1, partO1, partML, u0,
        nl_ww[1], nl_wb[1], m1, 4096, 8);

    // mot = lrelu(deconv(m1)) : [4][64][16384]  (fused epilogue)
    conv3x3_mfma<1, 1><<<4 * 256, 256, 0, stream>>>(
        m1, m1, 64, (size_t)2 * 64 * 4096, 64, 64, 64,
        w2_dec1, 576, 128, 16384, 256, 1, 18, regPart, dec_b1, 1, 64, mot);

    // est = conv3x3 s1 (mot; 64->27) : [4][27][16384]  (fused epilogue)
    conv3x3_mfma<1, 0><<<4 * 256, 256, 0, stream>>>(
        mot, mot, 64, (size_t)2 * 64 * 16384, 128, 128, 64,
        w2_est, 576, 128, 16384, 256, 1, 18, regPart, off_b, 0, 27, est);

    // ==== batched transpose (bf16) + batched deformable conv ====
    transpose_nhwc_bf16<<<8192, 256, 0, stream>>>(x_all, xTb);
    deform_mfma6<<<1024, 512, 0, stream>>>(xTb, est, wbf, dcn_b, out);
}